// Round 4
// baseline (235.989 us; speedup 1.0000x reference)
//
#include <hip/hip_runtime.h>
#include <hip/hip_bf16.h>

#define OMEGA0 30.0f
#define IN_DIM 512
#define OUT_DIM 512
#define BM 512
#define BN 128
#define THREADS 1024

typedef _Float16 f16;
typedef __attribute__((ext_vector_type(8))) _Float16 f16x8;
typedef __attribute__((ext_vector_type(4))) float f32x4;

// ---------------- pre-kernel 1: theta16[o][k] = f16(30*theta[o][k]) ----------------
__global__ void cvt_theta_kernel(const float* __restrict__ theta, f16* __restrict__ theta16) {
    int idx = (blockIdx.x * 256 + threadIdx.x) * 8;
    f32x4 a = *(const f32x4*)(theta + idx);
    f32x4 b = *(const f32x4*)(theta + idx + 4);
    f16x8 o;
#pragma unroll
    for (int i = 0; i < 4; i++) { o[i] = (f16)(OMEGA0 * a[i]); o[4 + i] = (f16)(OMEGA0 * b[i]); }
    *(f16x8*)(theta16 + idx) = o;
}

// ---------------- pre-kernel 2: bias[o] = 30*sum_k theta[o][k] + phi[o] ----------------
__global__ void make_bias_kernel(const float* __restrict__ theta, const float* __restrict__ phi,
                                 float* __restrict__ bias) {
    int w = threadIdx.x >> 6, lane = threadIdx.x & 63;
    int o = blockIdx.x * 4 + w;
    const float* row = theta + (long)o * IN_DIM + lane * 8;
    f32x4 a = *(const f32x4*)row;
    f32x4 b = *(const f32x4*)(row + 4);
    float s = a[0] + a[1] + a[2] + a[3] + b[0] + b[1] + b[2] + b[3];
#pragma unroll
    for (int off = 32; off; off >>= 1) s += __shfl_down(s, off, 64);
    if (lane == 0) bias[o] = OMEGA0 * s + phi[o];
}

// ---------------- main GEMM + cos epilogue ----------------
// Barrier-free tall-skinny GEMM. B n-tile (128 x K=512 f16 = 128 KB) resident in
// LDS for the whole block, staged ONCE (single barrier). 16 waves (1024 thr),
// wave-tile 32x128, each wave streams its 32 exclusive A rows global->reg with
// fp32->f16 cvt, depth-2 prefetch; 4 waves/SIMD provide TLP latency hiding.
// B LDS layout: per-(kk,fn) 1KB windows, chunk id == MFMA lane id -> every
// ds_read_b128 is a 64-lane contiguous 1KB burst (zero bank conflicts).
__launch_bounds__(THREADS, 4)
__global__ void siren_gemm_kernel(const float* __restrict__ x, const f16* __restrict__ theta16,
                                  const float* __restrict__ bias, float* __restrict__ out) {
    __shared__ f16 ldsB[128 * 512];   // 128 KB, window layout [(kk*8+fn)*512 + lane*8]

    // XCD-chunked swizzle (grid = 1024): the 4 n-tiles of an m-strip run
    // consecutively on one XCD -> x reuse via that XCD's L2 + L3.
    int nwg = gridDim.x;
    int bid = blockIdx.x;
    int cpx = nwg >> 3;
    int swz = (bid & 7) * cpx + (bid >> 3);
    int mt = swz >> 2;
    int nt = swz & 3;
    long m0 = (long)mt * BM;
    int n0 = nt * BN;

    int t = threadIdx.x;
    int w = t >> 6, lane = t & 63;
    int lr = lane & 15, lk = lane >> 4;

    // ---- one-time B stage: wave w stages windows (kk=w, fn=0..7) ----
    // Window (kk,fn), chunk l holds B[col=n0+fn*16+(l&15)][k=kk*32+(l>>4)*8 ..+8]
    // == exactly lane l's MFMA B-fragment. LDS dest is wave-uniform base +
    // lane*16 (hardware), global src per-lane.
    {
#pragma unroll
        for (int fn = 0; fn < 8; fn++) {
            const f16* p = theta16 + (long)(n0 + fn * 16 + lr) * IN_DIM + w * 32 + lk * 8;
            __builtin_amdgcn_global_load_lds(
                (const __attribute__((address_space(1))) char*)(const char*)p,
                (__attribute__((address_space(3))) char*)(char*)(&ldsB[(w * 8 + fn) * 512]),
                16, 0, 0);
        }
    }
    __syncthreads();   // the only barrier

    // ---- barrier-free K-loop ----
    f32x4 acc[2][8] = {};                       // 2 fm x 8 fn fragments (64 VGPR)
    const float* aBase = x + (m0 + w * 32 + lr) * (long)IN_DIM + lk * 8;

    f32x4 ar[2][2][2];                          // [slot][fm][half] (32 VGPR), static-indexed

    // prologue: issue k-chunks 0 and 1
#pragma unroll
    for (int s = 0; s < 2; s++)
#pragma unroll
        for (int fm = 0; fm < 2; fm++) {
            const float* p = aBase + (long)fm * 16 * IN_DIM + s * 32;
            ar[s][fm][0] = *(const f32x4*)p;
            ar[s][fm][1] = *(const f32x4*)(p + 4);
        }

#pragma unroll
    for (int kk = 0; kk < 16; kk++) {
        int slot = kk & 1;                      // compile-time after unroll
        f16x8 afrag[2];
#pragma unroll
        for (int fm = 0; fm < 2; fm++)
#pragma unroll
            for (int i = 0; i < 4; i++) {
                afrag[fm][i]     = (f16)ar[slot][fm][0][i];
                afrag[fm][4 + i] = (f16)ar[slot][fm][1][i];
            }
        if (kk + 2 < 16) {                      // depth-2 prefetch into freed slot
#pragma unroll
            for (int fm = 0; fm < 2; fm++) {
                const float* p = aBase + (long)fm * 16 * IN_DIM + (kk + 2) * 32;
                ar[slot][fm][0] = *(const f32x4*)p;
                ar[slot][fm][1] = *(const f32x4*)(p + 4);
            }
        }
#pragma unroll
        for (int fn = 0; fn < 8; fn++) {
            f16x8 bfrag = *(const f16x8*)&ldsB[(kk * 8 + fn) * 512 + lane * 8];
            acc[0][fn] = __builtin_amdgcn_mfma_f32_16x16x32_f16(afrag[0], bfrag, acc[0][fn], 0, 0, 0);
            acc[1][fn] = __builtin_amdgcn_mfma_f32_16x16x32_f16(afrag[1], bfrag, acc[1][fn], 0, 0, 0);
        }
    }

    // ---- epilogue: cos(acc + bias[col]) ----
#pragma unroll
    for (int fn = 0; fn < 8; fn++) {
        int col = n0 + fn * 16 + lr;
        float bv = bias[col];
#pragma unroll
        for (int fm = 0; fm < 2; fm++) {
            long row0 = m0 + w * 32 + fm * 16 + lk * 4;
#pragma unroll
            for (int r = 0; r < 4; r++)
                out[(row0 + r) * OUT_DIM + col] = __cosf(acc[fm][fn][r] + bv);
        }
    }
}

extern "C" void kernel_launch(void* const* d_in, const int* in_sizes, int n_in,
                              void* d_out, int out_size, void* d_ws, size_t ws_size,
                              hipStream_t stream) {
    const float* x     = (const float*)d_in[0];
    const float* theta = (const float*)d_in[1];
    const float* phi   = (const float*)d_in[2];
    float* out = (float*)d_out;

    size_t theta16_bytes = (size_t)OUT_DIM * IN_DIM * sizeof(f16);  // 512 KB
    size_t need = theta16_bytes + OUT_DIM * sizeof(float);          // + 2 KB bias
    if (ws_size < need) return;

    f16*   theta16 = (f16*)d_ws;
    float* bias    = (float*)((char*)d_ws + theta16_bytes);

    int Brows = in_sizes[0] / IN_DIM;  // 131072

    cvt_theta_kernel<<<(OUT_DIM * IN_DIM / 8 + 255) / 256, 256, 0, stream>>>(theta, theta16);
    make_bias_kernel<<<OUT_DIM / 4, 256, 0, stream>>>(theta, phi, bias);

    int grid = (Brows / BM) * (OUT_DIM / BN);  // 256 * 4 = 1024
    siren_gemm_kernel<<<grid, THREADS, 0, stream>>>(x, theta16, bias, out);
}